// Round 8
// baseline (171.877 us; speedup 1.0000x reference)
//
#include <hip/hip_runtime.h>
#include <hip/hip_bf16.h>

// GAT layer: B=2, N=2048, C_IN=128, H=16, c=8.
// E(i,j) = exp(lrelu(lp_i+lc_j))*2^-12 = max(P1_i*Q1_j, P2_i*Q2_j) & adjmask (f16).
// Aggregation: mfma_f32_16x16x32_f16; B-operand = [h feats | ones buffer].
// Round 22: r21 split retried with all three measured failures fixed.
//  prep: 1024 blk x 256 thr (16 waves/CU) pure streaming: adj -> adj_out copy
//   + byte-mask array (1B/edge) in attn's exact lane layout. ~75 MB ~ 12 us.
//   XCD swizzle aligned with attn so masks are consumed from the same L2.
//  attn: NO LDS, NO barriers, 16-row i-tiles -> 1024 blk x 256 thr =
//   4 blk/CU, 4 waves/SIMD. All streams (masks/q1q2/hQ) are 4-deep register
//   prefetch; per chunk: [issue loads ch+4] sched_barrier(0) [compute ch].
//   r20 proved sched_barrier pins loads (VGPR 36->68); r21 proved the
//   working set is cache-resident (FETCH 6.8 MB). VGPR_Count ~100-120 is the
//   validation signal that the pipeline survived compilation.
// d_out = [out: B*N*128][adj copy: B*N*N]

#define B_   2
#define N_   2048
#define CIN_ 128
#define H_   16

typedef _Float16 h2  __attribute__((ext_vector_type(2)));
typedef _Float16 v8h __attribute__((ext_vector_type(8)));
typedef float    v4f __attribute__((ext_vector_type(4)));

#define SC6 0.015625f   // 2^-6

__device__ inline h2 pk_f16(float a, float b) {
  return __builtin_bit_cast(h2, __builtin_amdgcn_cvt_pkrtz(a, b));
}
__device__ inline unsigned as_u32(h2 v) { return __builtin_bit_cast(unsigned, v); }
__device__ inline h2 as_h2(unsigned u) { return __builtin_bit_cast(h2, u); }

// 4 adjacency floats (exactly 0.0/1.0) -> 4 mask bytes 0x00/0xFF, j0 in byte0.
__device__ inline unsigned mask4(float4 f) {
  unsigned r = (unsigned)f.x | ((unsigned)f.y << 8) |
               ((unsigned)f.z << 16) | ((unsigned)f.w << 24);
  return (r << 8) - r;   // per-byte 0x01 -> 0xFF
}

__global__ __launch_bounds__(128) void proj_kernel(
    const float* __restrict__ nf, const float* __restrict__ W,
    const float* __restrict__ bias, const float* __restrict__ a,
    unsigned* __restrict__ hQ, unsigned* __restrict__ qI,
    float* __restrict__ lpT, unsigned* __restrict__ ones) {
  const int row0 = blockIdx.x * 4;       // 4 consecutive rows (same batch)
  const int t    = threadIdx.x;          // output column 0..127
  if (blockIdx.x == 0) {                 // ones-buffer for B-operand cols 8..15
    ones[t] = 0x3C003C00u; ones[t + 128] = 0x3C003C00u;
    ones[t + 256] = 0x3C003C00u; ones[t + 384] = 0x3C003C00u;
  }
  __shared__ float sNf[4][CIN_];
  ((float4*)&sNf[0][0])[t] = ((const float4*)(nf + (long)row0 * CIN_))[t];
  __syncthreads();
  float acc[4];
  const float bv = bias[t];
#pragma unroll
  for (int r = 0; r < 4; ++r) acc[r] = bv;
#pragma unroll 8
  for (int k = 0; k < CIN_; ++k) {
    const float w = W[k * 128 + t];
#pragma unroll
    for (int r = 0; r < 4; ++r) acc[r] = fmaf(sNf[r][k], w, acc[r]);
  }
  const int h = t >> 3, kc = t & 7;
  const int b = row0 >> 11, n0 = row0 & (N_ - 1);
  const int bh = b * H_ + h;
  const int cdw = n0 >> 1;               // j-pair dword index (2-aligned)
  uint2 hv;
  hv.x = as_u32(pk_f16(acc[0], acc[1]));
  hv.y = as_u32(pk_f16(acc[2], acc[3]));
  *(uint2*)(hQ + ((long)(bh * 8 + kc)) * (N_ / 2) + cdw) = hv;

  const float ap = a[h * 16 + kc], ac = a[h * 16 + 8 + kc];
  float lpv[4], lcv[4];
#pragma unroll
  for (int r = 0; r < 4; ++r) {
    float x = acc[r] * ap, y = acc[r] * ac;
#pragma unroll
    for (int s = 1; s < 8; s <<= 1) {
      x += __shfl_xor(x, s);
      y += __shfl_xor(y, s);
    }
    lpv[r] = x; lcv[r] = y;
  }
  if (kc == 0) {
    float4 l0 = {lpv[0], lpv[1], lpv[2], lpv[3]};
    *(float4*)(lpT + (long)bh * N_ + n0) = l0;
    uint2 q1, q2;
    q1.x = as_u32(pk_f16(__expf(lcv[0]) * SC6, __expf(lcv[1]) * SC6));
    q1.y = as_u32(pk_f16(__expf(lcv[2]) * SC6, __expf(lcv[3]) * SC6));
    q2.x = as_u32(pk_f16(__expf(0.2f * lcv[0]) * SC6, __expf(0.2f * lcv[1]) * SC6));
    q2.y = as_u32(pk_f16(__expf(0.2f * lcv[2]) * SC6, __expf(0.2f * lcv[3]) * SC6));
    // interleave: chunk(16 pairs)=32dw: [q1 quad0|q2 quad0|...|q1 quad3|q2 quad3]
    const int addr = bh * 2048 + (cdw >> 4) * 32 + ((cdw >> 2) & 3) * 8;
    const int off  = cdw & 3;            // 0 or 2
    *(uint2*)(qI + addr + off)     = q1;
    *(uint2*)(qI + addr + 4 + off) = q2;
  }
}

// Streaming pass: adj -> {adj_out copy, byte-mask array}.
// Mask layout per (b, it16) [8192 dw]: dw = ch*128 + (m*4+q)*2 + half,
// covering row it16*16+m, cols ch*32 + q*8 + half*4 .. +3.
// prep thread map t = r*8 + g (r=row 0..31, g=col-group): mask writes are
// 256B-contiguous per wave; adj read/write 128B segments x 8 per wave.
__global__ __launch_bounds__(256) void prep_kernel(
    const float* __restrict__ adj, float* __restrict__ adj_out,
    unsigned* __restrict__ mks) {
  const int L    = (blockIdx.x & 7) * 128 + (blockIdx.x >> 3);
  const int oct  = L & 7, it32 = (L >> 3) & 63, b = L >> 9;
  const int t    = threadIdx.x;
  const int g    = t & 7, r = t >> 3;    // col-group 0..7, row 0..31
  const int it16 = it32 * 2 + (r >> 4), m = r & 15;
  const int q    = g >> 1, half = g & 1;
  const long rbase = ((long)(b * N_) + it32 * 32 + r) * N_;
  unsigned* mb = mks + ((long)(b * 128 + it16)) * 8192;
#pragma unroll
  for (int c8 = 0; c8 < 8; ++c8) {
    const int ch  = oct * 8 + c8;
    const int col = ch * 32 + g * 4;
    const float4 fa = *(const float4*)(adj + rbase + col);
    *(float4*)(adj_out + rbase + col) = fa;
    mb[ch * 128 + (m * 4 + q) * 2 + half] = mask4(fa);
  }
}

__global__ __launch_bounds__(256, 4) void attn_kernel(
    const unsigned* __restrict__ hQ, const unsigned* __restrict__ qI,
    const float* __restrict__ lpT, const unsigned* __restrict__ ones,
    const unsigned* __restrict__ mks, float* __restrict__ out) {
  // XCD swizzle aligned with prep: stripe it16 lives on the same XCD L2.
  const int L  = (blockIdx.x & 7) * 128 + (blockIdx.x >> 3);
  const int hg = L & 3, it = (L >> 2) & 127, b = L >> 9;
  const int i0 = it * 16;
  const int t = threadIdx.x, w = t >> 6, lane = t & 63;
  const int m = lane & 15, q = lane >> 4;
  const int h = hg * 4 + w, bh = b * H_ + h;

  // per-row parent factors (rows i0+m)
  const float lp = lpT[(long)bh * N_ + i0 + m];
  const float e1 = __expf(lp) * SC6, e2 = __expf(0.2f * lp) * SC6;
  const h2 P1 = pk_f16(e1, e1), P2 = pk_f16(e2, e2);

  // streams
  const uint2* mp = (const uint2*)mks + ((long)(b * 128 + it)) * 4096 + (m * 4 + q);
  const unsigned* qp = qI + bh * 2048 + q * 8;
  const unsigned hmask = (m < 8) ? ~0u : 0u;
  const unsigned* hp = (m < 8)
      ? hQ + ((long)(bh * 8 + m)) * (N_ / 2) + q * 4
      : ones + q * 4;

  // 4-deep register prefetch for all streams
  uint2 bmk[4];
  uint4 bq1[4], bq2[4], bhq[4];
#pragma unroll
  for (int d = 0; d < 4; ++d) {
    bmk[d] = mp[d * 64];
    bq1[d] = *(const uint4*)(qp + d * 32);
    bq2[d] = *(const uint4*)(qp + d * 32 + 4);
    bhq[d] = *(const uint4*)(hp + ((d * 16) & hmask));
  }

  v4f acc = {0.f, 0.f, 0.f, 0.f};

#pragma unroll
  for (int ch = 0; ch < 64; ++ch) {
    const int p = ch & 3, f = (ch + 4) & 63;
    // issue loads for chunk ch+4 (wrap re-reads are harmless)
    const uint2 nmk = mp[f * 64];
    const uint4 nq1 = *(const uint4*)(qp + f * 32);
    const uint4 nq2 = *(const uint4*)(qp + f * 32 + 4);
    const uint4 nhq = *(const uint4*)(hp + ((f * 16) & hmask));
    __builtin_amdgcn_sched_barrier(0);   // pin: loads above, compute below

    const uint2 Mv = bmk[p];
    const unsigned ma = __builtin_amdgcn_perm(Mv.x, Mv.x, 0x01010000u);
    const unsigned mb = __builtin_amdgcn_perm(Mv.x, Mv.x, 0x03030202u);
    const unsigned mc = __builtin_amdgcn_perm(Mv.y, Mv.y, 0x01010000u);
    const unsigned md = __builtin_amdgcn_perm(Mv.y, Mv.y, 0x03030202u);

    const uint4 q1 = bq1[p], q2 = bq2[p];
    const v8h bf = __builtin_bit_cast(v8h, bhq[p]);
    const uint4 af = {
      as_u32(__builtin_elementwise_max(P1 * as_h2(q1.x), P2 * as_h2(q2.x))) & ma,
      as_u32(__builtin_elementwise_max(P1 * as_h2(q1.y), P2 * as_h2(q2.y))) & mb,
      as_u32(__builtin_elementwise_max(P1 * as_h2(q1.z), P2 * as_h2(q2.z))) & mc,
      as_u32(__builtin_elementwise_max(P1 * as_h2(q1.w), P2 * as_h2(q2.w))) & md};
    acc = __builtin_amdgcn_mfma_f32_16x16x32_f16(
        __builtin_bit_cast(v8h, af), bf, acc, 0, 0, 0);

    bmk[p] = nmk; bq1[p] = nq1; bq2[p] = nq2; bhq[p] = nhq;
  }

  // D: col = m (feature), row = q*4 + r (i-row). Denominator in col 8.
#pragma unroll
  for (int r = 0; r < 4; ++r) {
    const float sden = __shfl(acc[r], (lane & 48) | 8);
    if (m < 8) {
      const long gi = ((long)(b * N_ + i0 + q * 4 + r)) * H_ + h;
      out[gi * 8 + m] = acc[r] / sden;
    }
  }
}

extern "C" void kernel_launch(void* const* d_in, const int* in_sizes, int n_in,
                              void* d_out, int out_size, void* d_ws, size_t ws_size,
                              hipStream_t stream) {
  const float* nf   = (const float*)d_in[0];
  const float* adj  = (const float*)d_in[1];
  const float* W    = (const float*)d_in[2];
  const float* bias = (const float*)d_in[3];
  const float* a    = (const float*)d_in[4];

  float* out     = (float*)d_out;
  float* adj_out = out + (long)B_ * N_ * H_ * 8;    // 524288 offset

  unsigned* ws   = (unsigned*)d_ws;
  unsigned* hQ   = ws;                       // 262144 dw
  unsigned* qI   = ws + 262144;              // 65536 dw
  float*    lpT  = (float*)(ws + 327680);    // 65536 floats
  unsigned* ones = ws + 393216;              // 512 dw
  unsigned* mks  = ws + 393728;              // 2097152 dw (8.4 MB)

  hipLaunchKernelGGL(proj_kernel, dim3(B_ * N_ / 4), dim3(128), 0, stream,
                     nf, W, bias, a, hQ, qI, lpT, ones);
  hipLaunchKernelGGL(prep_kernel, dim3(1024), dim3(256), 0, stream,
                     adj, adj_out, mks);
  hipLaunchKernelGGL(attn_kernel, dim3(1024), dim3(256), 0, stream,
                     hQ, qI, lpT, ones, mks, out);
}